// Round 8
// baseline (1815.149 us; speedup 1.0000x reference)
//
#include <hip/hip_runtime.h>
#include <cmath>

#define DEV static __device__ __forceinline__

typedef _Float16 half_t;
typedef _Float16 half2_t __attribute__((ext_vector_type(2)));
typedef _Float16 half4_t __attribute__((ext_vector_type(4)));
typedef _Float16 half8_t __attribute__((ext_vector_type(8)));
typedef float f32x4 __attribute__((ext_vector_type(4)));

// ---------------- FiLM ----------------
__global__ void k_film(const float* __restrict__ gf,
                       const float* __restrict__ gW, const float* __restrict__ gb,
                       const float* __restrict__ bW, const float* __restrict__ bb,
                       float* __restrict__ out) {
  int j = threadIdx.x;
  if (j >= 64) return;
  float g = gb[j], b = bb[j];
  for (int k = 0; k < 128; ++k) {
    float v = gf[k];
    g += v * gW[k * 64 + j];
    b += v * bW[k * 64 + j];
  }
  out[j] = 1.0f + g;
  out[64 + j] = b;
}

// ---------------- input projection + FiLM ----------------
__global__ __launch_bounds__(256) void k_input(
    const float* __restrict__ nf, const float* __restrict__ ipW,
    const float* __restrict__ ipb, const float* __restrict__ gbv,
    float* __restrict__ x64, int N) {
  int lane = threadIdx.x & 63;
  int n = blockIdx.x * 4 + (threadIdx.x >> 6);
  if (n >= N) return;
  const float* row = nf + (size_t)n * 5;
  float acc = ipb[lane];
#pragma unroll
  for (int k = 0; k < 5; ++k) acc += row[k] * ipW[k * 64 + lane];
  acc = fmaxf(acc, 0.f);
  acc = acc * gbv[lane] + gbv[64 + lane];
  x64[(size_t)n * 64 + lane] = acc;
}

// ---------------- CSR build ----------------
__global__ void k_count(const int* __restrict__ dst, int* __restrict__ cnt, int E) {
  int e = blockIdx.x * 256 + threadIdx.x;
  if (e < E) atomicAdd(&cnt[dst[e]], 1);
}

__global__ void k_scan1(const int* __restrict__ cnt, int* __restrict__ off,
                        int* __restrict__ bsum, int N) {
  __shared__ int s[256];
  int tid = threadIdx.x;
  int i = blockIdx.x * 256 + tid;
  int v = (i < N) ? cnt[i] : 0;
  s[tid] = v;
  __syncthreads();
  int x = v;
  for (int d = 1; d < 256; d <<= 1) {
    int t = (tid >= d) ? s[tid - d] : 0;
    __syncthreads();
    x += t;
    s[tid] = x;
    __syncthreads();
  }
  if (i < N) off[i] = x - v;
  if (tid == 255) bsum[blockIdx.x] = x;
}

__global__ void k_scan2(int* __restrict__ bsum, int nb) {
  __shared__ int s[256];
  int tid = threadIdx.x;
  int v = (tid < nb) ? bsum[tid] : 0;
  s[tid] = v;
  __syncthreads();
  int x = v;
  for (int d = 1; d < 256; d <<= 1) {
    int t = (tid >= d) ? s[tid - d] : 0;
    __syncthreads();
    x += t;
    s[tid] = x;
    __syncthreads();
  }
  if (tid < nb) bsum[tid] = x - v;
}

__global__ void k_scan3(int* __restrict__ off, const int* __restrict__ bsum, int N, int E) {
  int i = blockIdx.x * 256 + threadIdx.x;
  if (i < N) off[i] += bsum[blockIdx.x];
  if (i == 0) off[N] = E;
}

__global__ void k_scatter(const int* __restrict__ dst, const int* __restrict__ off,
                          int* __restrict__ cur, int* __restrict__ eid, int E) {
  int e = blockIdx.x * 256 + threadIdx.x;
  if (e < E) {
    int d = dst[e];
    int p = atomicAdd(&cur[d], 1);
    eid[off[d] + p] = e;
  }
}

// ---------------- edge encoder -> CSR order, half precision output ----------------
__global__ __launch_bounds__(256) void k_edgefeat(
    const float* __restrict__ pos, const int* __restrict__ src, const int* __restrict__ dst,
    const int* __restrict__ eid,
    const float* __restrict__ W1, const float* __restrict__ b1,
    const float* __restrict__ W2, const float* __restrict__ b2,
    half_t* __restrict__ ef_csr, int* __restrict__ src_csr, int E) {
  __shared__ float sW1[160], sb1[32], sW2[1024], sb2[32];
  for (int i = threadIdx.x; i < 160; i += 256) sW1[i] = W1[i];
  for (int i = threadIdx.x; i < 1024; i += 256) sW2[i] = W2[i];
  if (threadIdx.x < 32) { sb1[threadIdx.x] = b1[threadIdx.x]; sb2[threadIdx.x] = b2[threadIdx.x]; }
  __syncthreads();
  int t = blockIdx.x * 256 + threadIdx.x;
  if (t >= E) return;
  int e = eid[t];
  int s = src[e], d = dst[e];
  src_csr[t] = s;
  float dx = pos[d * 3 + 0] - pos[s * 3 + 0];
  float dy = pos[d * 3 + 1] - pos[s * 3 + 1];
  float dz = pos[d * 3 + 2] - pos[s * 3 + 2];
  float dist = sqrtf(dx * dx + dy * dy + dz * dz);
  dist = fmaxf(dist, 1e-6f);
  float inv = 1.f / dist;
  float attr[5] = {dx * inv, dy * inv, dz * inv, dist, logf(dist)};
  float h[32];
#pragma unroll
  for (int j = 0; j < 32; ++j) {
    float a = sb1[j];
#pragma unroll
    for (int k = 0; k < 5; ++k) a += attr[k] * sW1[k * 32 + j];
    h[j] = fmaxf(a, 0.f);
  }
  half_t hv[32];
#pragma unroll 4
  for (int j = 0; j < 32; ++j) {
    float a = sb2[j];
#pragma unroll
    for (int k = 0; k < 32; ++k) a += h[k] * sW2[k * 32 + j];
    hv[j] = (half_t)a;
  }
  uint4* ov = (uint4*)(ef_csr + (size_t)t * 32);
  const uint4* iv = (const uint4*)hv;
  ov[0] = iv[0]; ov[1] = iv[1]; ov[2] = iv[2]; ov[3] = iv[3];
}

// ---------------- batched weight prep: fp32 (K x 256) -> f16 transposed (256 x K) ----------------
__global__ __launch_bounds__(256) void k_prepAll(
    const float* __restrict__ l0Wl, const float* __restrict__ l0Wr,
    const float* __restrict__ resW, const float* __restrict__ Wl,
    const float* __restrict__ Wr, const float* __restrict__ We,
    half_t* __restrict__ btL0l, half_t* __restrict__ btL0r, half_t* __restrict__ btRes,
    half_t* __restrict__ btWl, half_t* __restrict__ btWr, half_t* __restrict__ wet) {
  int m = blockIdx.y;
  const float* W;
  half_t* Bt;
  int K;
  if (m == 0)      { W = l0Wl; Bt = btL0l; K = 64; }
  else if (m == 1) { W = l0Wr; Bt = btL0r; K = 64; }
  else if (m == 2) { W = resW; Bt = btRes; K = 64; }
  else if (m < 8)  { int i = m - 3;  W = Wl + (size_t)i * 65536; Bt = btWl + (size_t)i * 65536; K = 256; }
  else if (m < 13) { int i = m - 8;  W = Wr + (size_t)i * 65536; Bt = btWr + (size_t)i * 65536; K = 256; }
  else             { int i = m - 13; W = We + (size_t)i * 8192;  Bt = wet + (size_t)i * 8192;  K = 32; }
  int i = blockIdx.x * 256 + threadIdx.x;
  if (i < K * 256) {
    int k = i >> 8, c = i & 255;
    Bt[(size_t)c * K + k] = (half_t)W[i];
  }
}

// ---------------- MFMA f16 GEMM body (shared, templated output type) ----------------
template <typename OutT>
DEV void gemm16_body(const float* __restrict__ A, const half_t* __restrict__ Bt,
                     const float* __restrict__ bias, OutT* __restrict__ C,
                     int M, int K, int bx, int bcol, int tid) {
  int w = tid >> 6, lane = tid & 63;
  int r16 = lane & 15, kg = lane >> 4;
  int arow = bx * 64 + w * 16 + r16;
  int arowc = arow < M ? arow : M - 1;
  f32x4 acc[4] = {};
  const int nks = K >> 5;
  const float* ap = A + (size_t)arowc * K + kg * 8;
  for (int ks = 0; ks < nks; ++ks) {
    float4 a0 = *(const float4*)(ap + ks * 32);
    float4 a1 = *(const float4*)(ap + ks * 32 + 4);
    half8_t af;
    af[0] = (half_t)a0.x; af[1] = (half_t)a0.y; af[2] = (half_t)a0.z; af[3] = (half_t)a0.w;
    af[4] = (half_t)a1.x; af[5] = (half_t)a1.y; af[6] = (half_t)a1.z; af[7] = (half_t)a1.w;
    int k0 = ks * 32 + kg * 8;
#pragma unroll
    for (int nt = 0; nt < 4; ++nt) {
      half8_t bf = *(const half8_t*)(Bt + (size_t)(bcol + nt * 16 + r16) * K + k0);
      acc[nt] = __builtin_amdgcn_mfma_f32_16x16x32_f16(af, bf, acc[nt], 0, 0, 0);
    }
  }
  int orow0 = bx * 64 + w * 16 + kg * 4;
#pragma unroll
  for (int nt = 0; nt < 4; ++nt) {
    int gcol = bcol + nt * 16 + r16;
    float bv = bias[gcol];
#pragma unroll
    for (int r = 0; r < 4; ++r) {
      int grow = orow0 + r;
      if (grow < M) C[(size_t)grow * 256 + gcol] = (OutT)(acc[nt][r] + bv);
    }
  }
}

__global__ __launch_bounds__(256) void k_gemm16(
    const float* __restrict__ A, const half_t* __restrict__ Bt,
    const float* __restrict__ bias, float* __restrict__ C, int M, int K) {
  gemm16_body<float>(A, Bt, bias, C, M, K, blockIdx.x, blockIdx.y * 64, threadIdx.x);
}

// xl (f16 out) and xr (f32 out) in one launch: by 0..3 -> xl, by 4..7 -> xr
__global__ __launch_bounds__(256) void k_gemm16x2(
    const float* __restrict__ A, const half_t* __restrict__ btl,
    const half_t* __restrict__ btr, const float* __restrict__ bl,
    const float* __restrict__ br, half_t* __restrict__ xl, float* __restrict__ xr,
    int M, int K) {
  if (blockIdx.y < 4)
    gemm16_body<half_t>(A, btl, bl, xl, M, K, blockIdx.x, blockIdx.y * 64, threadIdx.x);
  else
    gemm16_body<float>(A, btr, br, xr, M, K, blockIdx.x, (blockIdx.y - 4) * 64, threadIdx.x);
}

// ---------------- fused GATv2 layer ----------------
// 2 waves per node (block = 512 = 8 waves = 4 nodes). Each wave handles half the
// node's CSR edge range; max-free softmax partials (s, a4) merged via LDS.
// Lane owns 4 contiguous channels of head h = lane>>4. xl gathered as f16 (8B/lane).
__global__ __launch_bounds__(512) void k_fused(
    const int* __restrict__ off, const int* __restrict__ src_csr,
    const half_t* __restrict__ ef_csr,
    const half_t* __restrict__ xl, const float* __restrict__ xr,
    const float* __restrict__ xprev,
    const half_t* __restrict__ Wet_l, const float* __restrict__ att_l,
    const float* __restrict__ convb, const float* __restrict__ lng,
    const float* __restrict__ lnb,
    float* __restrict__ xout, int N) {
  __shared__ float4 lds_a[8][64];
  __shared__ float lds_s[8][64];
  int tid = threadIdx.x;
  int lane = tid & 63;
  int wid = tid >> 6;            // 0..7
  int hf = wid & 1;              // which half of the edge list
  int n = blockIdx.x * 4 + (wid >> 1);
  bool active = n < N;
  if (!active) n = N - 1;
  n = __builtin_amdgcn_readfirstlane(n);
  int h = lane >> 4, c0 = lane & 15;
  int ch0 = h * 64 + (c0 << 2);
  // w2[q][cc]: k-pair q of We column (ch0+cc), straight from f16 Wet ([256][32])
  half2_t w2[16][4];
#pragma unroll
  for (int cc = 0; cc < 4; ++cc) {
    const uint4* wp = (const uint4*)(Wet_l + (size_t)(ch0 + cc) * 32);
    uint4 q0 = wp[0], q1 = wp[1], q2 = wp[2], q3 = wp[3];
    w2[0][cc]  = __builtin_bit_cast(half2_t, q0.x);
    w2[1][cc]  = __builtin_bit_cast(half2_t, q0.y);
    w2[2][cc]  = __builtin_bit_cast(half2_t, q0.z);
    w2[3][cc]  = __builtin_bit_cast(half2_t, q0.w);
    w2[4][cc]  = __builtin_bit_cast(half2_t, q1.x);
    w2[5][cc]  = __builtin_bit_cast(half2_t, q1.y);
    w2[6][cc]  = __builtin_bit_cast(half2_t, q1.z);
    w2[7][cc]  = __builtin_bit_cast(half2_t, q1.w);
    w2[8][cc]  = __builtin_bit_cast(half2_t, q2.x);
    w2[9][cc]  = __builtin_bit_cast(half2_t, q2.y);
    w2[10][cc] = __builtin_bit_cast(half2_t, q2.z);
    w2[11][cc] = __builtin_bit_cast(half2_t, q2.w);
    w2[12][cc] = __builtin_bit_cast(half2_t, q3.x);
    w2[13][cc] = __builtin_bit_cast(half2_t, q3.y);
    w2[14][cc] = __builtin_bit_cast(half2_t, q3.z);
    w2[15][cc] = __builtin_bit_cast(half2_t, q3.w);
  }
  float4 att4 = *(const float4*)(att_l + ch0);
  float4 a06, a04;
  a06.x = 0.6f * att4.x; a06.y = 0.6f * att4.y; a06.z = 0.6f * att4.z; a06.w = 0.6f * att4.w;
  a04.x = 0.4f * att4.x; a04.y = 0.4f * att4.y; a04.z = 0.4f * att4.z; a04.w = 0.4f * att4.w;
  float4 xr4 = *(const float4*)(xr + (size_t)n * 256 + ch0);
  int o0 = off[n], o1 = off[n + 1];
  int deg = o1 - o0;
  int mid = o0 + ((deg + 1) >> 1);
  int ra = hf ? mid : o0;
  int rb = hf ? o1 : mid;
  float s = 0.f;
  float4 a4 = {0.f, 0.f, 0.f, 0.f};

#define XLF(SRC, DST)                                                                \
  float4 DST;                                                                        \
  {                                                                                  \
    half4_t _h = *(const half4_t*)(xl + (size_t)(SRC) * 256 + ch0);                  \
    DST.x = (float)_h[0]; DST.y = (float)_h[1];                                      \
    DST.z = (float)_h[2]; DST.w = (float)_h[3];                                      \
  }

#define GATE(T, XL, P)                                                               \
  {                                                                                  \
    const uint4* efq = (const uint4*)(ef_csr + (size_t)(T) * 32);                    \
    uint4 fa = efq[0], fb = efq[1], fc = efq[2], fd = efq[3];                        \
    uint fw[16] = {fa.x, fa.y, fa.z, fa.w, fb.x, fb.y, fb.z, fb.w,                   \
                   fc.x, fc.y, fc.z, fc.w, fd.x, fd.y, fd.z, fd.w};                  \
    float e0 = (XL).x + xr4.x, e1 = (XL).y + xr4.y;                                  \
    float e2 = (XL).z + xr4.z, e3 = (XL).w + xr4.w;                                  \
    _Pragma("unroll") for (int q = 0; q < 16; ++q) {                                 \
      half2_t f = __builtin_bit_cast(half2_t, fw[q]);                                \
      e0 = __builtin_amdgcn_fdot2(f, w2[q][0], e0, false);                           \
      e1 = __builtin_amdgcn_fdot2(f, w2[q][1], e1, false);                           \
      e2 = __builtin_amdgcn_fdot2(f, w2[q][2], e2, false);                           \
      e3 = __builtin_amdgcn_fdot2(f, w2[q][3], e3, false);                           \
    }                                                                                \
    P = a06.x * e0 + a04.x * fabsf(e0);                                              \
    P += a06.y * e1 + a04.y * fabsf(e1);                                             \
    P += a06.z * e2 + a04.z * fabsf(e2);                                             \
    P += a06.w * e3 + a04.w * fabsf(e3);                                             \
  }

  int t = ra;
  int npairs = (rb - ra) >> 1;
  if (npairs > 0) {
    int sA = src_csr[t], sB = src_csr[t + 1];
    XLF(sA, xlA);
    XLF(sB, xlB);
    for (int p = 0; p < npairs - 1; ++p, t += 2) {
      int sC = src_csr[t + 2], sD = src_csr[t + 3];
      XLF(sC, xlC);
      XLF(sD, xlD);
      float pA, pB;
      GATE(t, xlA, pA);
      GATE(t + 1, xlB, pB);
#pragma unroll
      for (int d = 1; d < 16; d <<= 1) {
        pA += __shfl_xor(pA, d);
        pB += __shfl_xor(pB, d);
      }
      float wA = __expf(pA), wB = __expf(pB);
      s += wA + wB;
      a4.x += wA * xlA.x + wB * xlB.x;
      a4.y += wA * xlA.y + wB * xlB.y;
      a4.z += wA * xlA.z + wB * xlB.z;
      a4.w += wA * xlA.w + wB * xlB.w;
      xlA = xlC; xlB = xlD;
    }
    {
      float pA, pB;
      GATE(t, xlA, pA);
      GATE(t + 1, xlB, pB);
#pragma unroll
      for (int d = 1; d < 16; d <<= 1) {
        pA += __shfl_xor(pA, d);
        pB += __shfl_xor(pB, d);
      }
      float wA = __expf(pA), wB = __expf(pB);
      s += wA + wB;
      a4.x += wA * xlA.x + wB * xlB.x;
      a4.y += wA * xlA.y + wB * xlB.y;
      a4.z += wA * xlA.z + wB * xlB.z;
      a4.w += wA * xlA.w + wB * xlB.w;
      t += 2;
    }
  }
  if (t < rb) {
    int sA = src_csr[t];
    XLF(sA, xlA);
    float pA;
    GATE(t, xlA, pA);
#pragma unroll
    for (int d = 1; d < 16; d <<= 1) pA += __shfl_xor(pA, d);
    float wA = __expf(pA);
    s += wA;
    a4.x += wA * xlA.x;
    a4.y += wA * xlA.y;
    a4.z += wA * xlA.z;
    a4.w += wA * xlA.w;
  }
#undef GATE
#undef XLF

  // merge the two half-partials via LDS
  lds_a[wid][lane] = a4;
  lds_s[wid][lane] = s;
  __syncthreads();
  if (hf != 0 || !active) return;
  float4 o4 = lds_a[wid ^ 1][lane];
  a4.x += o4.x; a4.y += o4.y; a4.z += o4.z; a4.w += o4.w;
  s += lds_s[wid ^ 1][lane];

  float inv = (deg > 0) ? 1.f / s : 0.f;
  float4 cb4 = *(const float4*)(convb + ch0);
  float4 v4;
  v4.x = a4.x * inv + cb4.x;
  v4.y = a4.y * inv + cb4.y;
  v4.z = a4.z * inv + cb4.z;
  v4.w = a4.w * inv + cb4.w;
  float ssum = v4.x + v4.y + v4.z + v4.w;
  float ssq = v4.x * v4.x + v4.y * v4.y + v4.z * v4.z + v4.w * v4.w;
#pragma unroll
  for (int d = 1; d < 64; d <<= 1) {
    ssum += __shfl_xor(ssum, d);
    ssq += __shfl_xor(ssq, d);
  }
  float mu = ssum * (1.0f / 256.0f);
  float var = ssq * (1.0f / 256.0f) - mu * mu;
  float rstd = rsqrtf(var + 1e-5f);
  float4 g4 = *(const float4*)(lng + ch0);
  float4 b4 = *(const float4*)(lnb + ch0);
  float4 xp4 = *(const float4*)(xprev + (size_t)n * 256 + ch0);
  float4 out4;
  out4.x = fmaxf((v4.x - mu) * rstd * g4.x + b4.x, 0.f) + xp4.x;
  out4.y = fmaxf((v4.y - mu) * rstd * g4.y + b4.y, 0.f) + xp4.y;
  out4.z = fmaxf((v4.z - mu) * rstd * g4.z + b4.z, 0.f) + xp4.z;
  out4.w = fmaxf((v4.w - mu) * rstd * g4.w + b4.w, 0.f) + xp4.w;
  *(float4*)(xout + (size_t)n * 256 + ch0) = out4;
}

// ---------------- output projection ----------------
__global__ __launch_bounds__(256) void k_out(
    const float* __restrict__ x, const float* __restrict__ W1, const float* __restrict__ b1,
    const float* __restrict__ W2, const float* __restrict__ b2,
    float* __restrict__ out, int N) {
  __shared__ float sW1[256 * 64];  // 64 KB
  for (int i = threadIdx.x; i < 256 * 64; i += 256) sW1[i] = W1[i];
  __syncthreads();
  int lane = threadIdx.x & 63;
  int wv = threadIdx.x >> 6;
  for (int n = blockIdx.x * 4 + wv; n < N; n += gridDim.x * 4) {
    const float* xrow = x + (size_t)n * 256;
    float h = b1[lane];
    for (int k = 0; k < 256; ++k) h += xrow[k] * sW1[k * 64 + lane];
    h = fmaxf(h, 0.f);
    float y[5];
#pragma unroll
    for (int o = 0; o < 5; ++o) {
      float p = h * W2[lane * 5 + o];
#pragma unroll
      for (int d = 1; d < 64; d <<= 1) p += __shfl_xor(p, d);
      y[o] = p;
    }
    if (lane == 0) {
#pragma unroll
      for (int o = 0; o < 5; ++o) out[(size_t)n * 5 + o] = y[o] + b2[o];
    }
  }
}

extern "C" void kernel_launch(void* const* d_in, const int* in_sizes, int n_in,
                              void* d_out, int out_size, void* d_ws, size_t ws_size,
                              hipStream_t stream) {
  const float* nf      = (const float*)d_in[0];
  const float* gf      = (const float*)d_in[1];
  const int*   eidx    = (const int*)d_in[2];
  const float* pos     = (const float*)d_in[3];
  const float* ip_W    = (const float*)d_in[4];
  const float* ip_b    = (const float*)d_in[5];
  const float* film_gW = (const float*)d_in[6];
  const float* film_gb = (const float*)d_in[7];
  const float* film_bW = (const float*)d_in[8];
  const float* film_bb = (const float*)d_in[9];
  const float* ee_W1   = (const float*)d_in[10];
  const float* ee_b1   = (const float*)d_in[11];
  const float* ee_W2   = (const float*)d_in[12];
  const float* ee_b2   = (const float*)d_in[13];
  const float* res_W   = (const float*)d_in[14];
  const float* res_b   = (const float*)d_in[15];
  const float* l0_Wl   = (const float*)d_in[16];
  const float* l0_bl   = (const float*)d_in[17];
  const float* l0_Wr   = (const float*)d_in[18];
  const float* l0_br   = (const float*)d_in[19];
  const float* Wl      = (const float*)d_in[20];
  const float* bl      = (const float*)d_in[21];
  const float* Wr      = (const float*)d_in[22];
  const float* br      = (const float*)d_in[23];
  const float* We      = (const float*)d_in[24];
  const float* att     = (const float*)d_in[25];
  const float* conv_b  = (const float*)d_in[26];
  const float* ln_g    = (const float*)d_in[27];
  const float* ln_b    = (const float*)d_in[28];
  const float* op_W1   = (const float*)d_in[29];
  const float* op_b1   = (const float*)d_in[30];
  const float* op_W2   = (const float*)d_in[31];
  const float* op_b2   = (const float*)d_in[32];

  const int N = in_sizes[0] / 5;
  const int E = in_sizes[2] / 2;
  const int* src = eidx;
  const int* dst = eidx + E;

  float* ws = (float*)d_ws;
  size_t o = 0;
  auto alloc = [&](size_t nflt) {
    float* p = ws + o;
    o += (nflt + 63) & ~(size_t)63;
    return p;
  };
  float* gb      = alloc(128);
  float* x64     = alloc((size_t)N * 64);
  half_t* ef_csr = (half_t*)alloc((size_t)E * 16);  // E*32 halfs
  int*   src_csr = (int*)alloc((size_t)E);
  int*   cnt     = (int*)alloc(2 * (size_t)N);
  int*   cur     = cnt + N;
  int*   csroff  = (int*)alloc((size_t)N + 1);
  int*   csreid  = (int*)alloc((size_t)E);
  int*   bsum    = (int*)alloc(256);
  half_t* xl     = (half_t*)alloc((size_t)N * 128);  // N*256 halfs
  float* xr      = alloc((size_t)N * 256);
  float* xA      = alloc((size_t)N * 256);
  float* xB      = alloc((size_t)N * 256);
  float* xp0     = alloc((size_t)N * 256);
  half_t* btL0l  = (half_t*)alloc(256 * 64 / 2);
  half_t* btL0r  = (half_t*)alloc(256 * 64 / 2);
  half_t* btRes  = (half_t*)alloc(256 * 64 / 2);
  half_t* btWl   = (half_t*)alloc(5 * 256 * 256 / 2);
  half_t* btWr   = (half_t*)alloc(5 * 256 * 256 / 2);
  half_t* wet    = (half_t*)alloc(6 * 256 * 32 / 2);  // We^T per layer: [256][32] f16

  (void)ws_size; (void)n_in; (void)out_size;

  hipMemsetAsync(cnt, 0, 2 * (size_t)N * sizeof(int), stream);

  const int nbN = (N + 255) / 256;
  k_film<<<1, 64, 0, stream>>>(gf, film_gW, film_gb, film_bW, film_bb, gb);
  k_input<<<(N + 3) / 4, 256, 0, stream>>>(nf, ip_W, ip_b, gb, x64, N);
  k_count<<<(E + 255) / 256, 256, 0, stream>>>(dst, cnt, E);
  k_scan1<<<nbN, 256, 0, stream>>>(cnt, csroff, bsum, N);
  k_scan2<<<1, 256, 0, stream>>>(bsum, nbN);
  k_scan3<<<nbN, 256, 0, stream>>>(csroff, bsum, N, E);
  k_scatter<<<(E + 255) / 256, 256, 0, stream>>>(dst, csroff, cur, csreid, E);
  k_edgefeat<<<(E + 255) / 256, 256, 0, stream>>>(pos, src, dst, csreid,
      ee_W1, ee_b1, ee_W2, ee_b2, ef_csr, src_csr, E);

  k_prepAll<<<dim3(256, 19), 256, 0, stream>>>(l0_Wl, l0_Wr, res_W, Wl, Wr, We,
                                               btL0l, btL0r, btRes, btWl, btWr, wet);

  const float* xin = x64;
  for (int layer = 0; layer < 6; ++layer) {
    const int K = (layer == 0) ? 64 : 256;
    const half_t* btl = (layer == 0) ? btL0l : (btWl + (size_t)(layer - 1) * 256 * 256);
    const half_t* btr = (layer == 0) ? btL0r : (btWr + (size_t)(layer - 1) * 256 * 256);
    const float* bl_p = (layer == 0) ? l0_bl : (bl + (size_t)(layer - 1) * 256);
    const float* br_p = (layer == 0) ? l0_br : (br + (size_t)(layer - 1) * 256);

    dim3 gg2((N + 63) / 64, 8);
    k_gemm16x2<<<gg2, 256, 0, stream>>>(xin, btl, btr, bl_p, br_p, xl, xr, N, K);

    const float* prev;
    if (layer == 0) {
      dim3 gg((N + 63) / 64, 4);
      k_gemm16<<<gg, 256, 0, stream>>>(xin, btRes, res_b, xp0, N, 64);
      prev = xp0;
    } else {
      prev = xin;
    }

    float* xout = (layer & 1) ? xB : xA;
    k_fused<<<(N + 3) / 4, 512, 0, stream>>>(
        csroff, src_csr, ef_csr, xl, xr, prev,
        wet + (size_t)layer * 256 * 32, att + (size_t)layer * 256,
        conv_b + (size_t)layer * 256, ln_g + (size_t)layer * 256, ln_b + (size_t)layer * 256,
        xout, N);
    xin = xout;
  }

  k_out<<<512, 256, 0, stream>>>(xin, op_W1, op_b1, op_W2, op_b2, (float*)d_out, N);
}

// Round 9
// 1201.087 us; speedup vs baseline: 1.5113x; 1.5113x over previous
//
#include <hip/hip_runtime.h>
#include <cmath>

#define DEV static __device__ __forceinline__

typedef _Float16 half_t;
typedef _Float16 half2_t __attribute__((ext_vector_type(2)));
typedef _Float16 half4_t __attribute__((ext_vector_type(4)));
typedef _Float16 half8_t __attribute__((ext_vector_type(8)));
typedef float f32x4 __attribute__((ext_vector_type(4)));

// ---------------- FiLM ----------------
__global__ void k_film(const float* __restrict__ gf,
                       const float* __restrict__ gW, const float* __restrict__ gb,
                       const float* __restrict__ bW, const float* __restrict__ bb,
                       float* __restrict__ out) {
  int j = threadIdx.x;
  if (j >= 64) return;
  float g = gb[j], b = bb[j];
  for (int k = 0; k < 128; ++k) {
    float v = gf[k];
    g += v * gW[k * 64 + j];
    b += v * bW[k * 64 + j];
  }
  out[j] = 1.0f + g;
  out[64 + j] = b;
}

// ---------------- input projection + FiLM ----------------
__global__ __launch_bounds__(256) void k_input(
    const float* __restrict__ nf, const float* __restrict__ ipW,
    const float* __restrict__ ipb, const float* __restrict__ gbv,
    float* __restrict__ x64, int N) {
  int lane = threadIdx.x & 63;
  int n = blockIdx.x * 4 + (threadIdx.x >> 6);
  if (n >= N) return;
  const float* row = nf + (size_t)n * 5;
  float acc = ipb[lane];
#pragma unroll
  for (int k = 0; k < 5; ++k) acc += row[k] * ipW[k * 64 + lane];
  acc = fmaxf(acc, 0.f);
  acc = acc * gbv[lane] + gbv[64 + lane];
  x64[(size_t)n * 64 + lane] = acc;
}

// ---------------- CSR build ----------------
__global__ void k_count(const int* __restrict__ dst, int* __restrict__ cnt, int E) {
  int e = blockIdx.x * 256 + threadIdx.x;
  if (e < E) atomicAdd(&cnt[dst[e]], 1);
}

__global__ void k_scan1(const int* __restrict__ cnt, int* __restrict__ off,
                        int* __restrict__ bsum, int N) {
  __shared__ int s[256];
  int tid = threadIdx.x;
  int i = blockIdx.x * 256 + tid;
  int v = (i < N) ? cnt[i] : 0;
  s[tid] = v;
  __syncthreads();
  int x = v;
  for (int d = 1; d < 256; d <<= 1) {
    int t = (tid >= d) ? s[tid - d] : 0;
    __syncthreads();
    x += t;
    s[tid] = x;
    __syncthreads();
  }
  if (i < N) off[i] = x - v;
  if (tid == 255) bsum[blockIdx.x] = x;
}

__global__ void k_scan2(int* __restrict__ bsum, int nb) {
  __shared__ int s[256];
  int tid = threadIdx.x;
  int v = (tid < nb) ? bsum[tid] : 0;
  s[tid] = v;
  __syncthreads();
  int x = v;
  for (int d = 1; d < 256; d <<= 1) {
    int t = (tid >= d) ? s[tid - d] : 0;
    __syncthreads();
    x += t;
    s[tid] = x;
    __syncthreads();
  }
  if (tid < nb) bsum[tid] = x - v;
}

__global__ void k_scan3(int* __restrict__ off, const int* __restrict__ bsum, int N, int E) {
  int i = blockIdx.x * 256 + threadIdx.x;
  if (i < N) off[i] += bsum[blockIdx.x];
  if (i == 0) off[N] = E;
}

__global__ void k_scatter(const int* __restrict__ dst, const int* __restrict__ off,
                          int* __restrict__ cur, int* __restrict__ eid, int E) {
  int e = blockIdx.x * 256 + threadIdx.x;
  if (e < E) {
    int d = dst[e];
    int p = atomicAdd(&cur[d], 1);
    eid[off[d] + p] = e;
  }
}

// ---------------- edge encoder -> CSR order, half precision output ----------------
__global__ __launch_bounds__(256) void k_edgefeat(
    const float* __restrict__ pos, const int* __restrict__ src, const int* __restrict__ dst,
    const int* __restrict__ eid,
    const float* __restrict__ W1, const float* __restrict__ b1,
    const float* __restrict__ W2, const float* __restrict__ b2,
    half_t* __restrict__ ef_csr, int* __restrict__ src_csr, int E) {
  __shared__ float sW1[160], sb1[32], sW2[1024], sb2[32];
  for (int i = threadIdx.x; i < 160; i += 256) sW1[i] = W1[i];
  for (int i = threadIdx.x; i < 1024; i += 256) sW2[i] = W2[i];
  if (threadIdx.x < 32) { sb1[threadIdx.x] = b1[threadIdx.x]; sb2[threadIdx.x] = b2[threadIdx.x]; }
  __syncthreads();
  int t = blockIdx.x * 256 + threadIdx.x;
  if (t >= E) return;
  int e = eid[t];
  int s = src[e], d = dst[e];
  src_csr[t] = s;
  float dx = pos[d * 3 + 0] - pos[s * 3 + 0];
  float dy = pos[d * 3 + 1] - pos[s * 3 + 1];
  float dz = pos[d * 3 + 2] - pos[s * 3 + 2];
  float dist = sqrtf(dx * dx + dy * dy + dz * dz);
  dist = fmaxf(dist, 1e-6f);
  float inv = 1.f / dist;
  float attr[5] = {dx * inv, dy * inv, dz * inv, dist, logf(dist)};
  float h[32];
#pragma unroll
  for (int j = 0; j < 32; ++j) {
    float a = sb1[j];
#pragma unroll
    for (int k = 0; k < 5; ++k) a += attr[k] * sW1[k * 32 + j];
    h[j] = fmaxf(a, 0.f);
  }
  half_t hv[32];
#pragma unroll 4
  for (int j = 0; j < 32; ++j) {
    float a = sb2[j];
#pragma unroll
    for (int k = 0; k < 32; ++k) a += h[k] * sW2[k * 32 + j];
    hv[j] = (half_t)a;
  }
  uint4* ov = (uint4*)(ef_csr + (size_t)t * 32);
  const uint4* iv = (const uint4*)hv;
  ov[0] = iv[0]; ov[1] = iv[1]; ov[2] = iv[2]; ov[3] = iv[3];
}

// ---------------- batched weight prep: fp32 (K x 256) -> f16 transposed (256 x K) ----------------
__global__ __launch_bounds__(256) void k_prepAll(
    const float* __restrict__ l0Wl, const float* __restrict__ l0Wr,
    const float* __restrict__ resW, const float* __restrict__ Wl,
    const float* __restrict__ Wr, const float* __restrict__ We,
    half_t* __restrict__ btL0l, half_t* __restrict__ btL0r, half_t* __restrict__ btRes,
    half_t* __restrict__ btWl, half_t* __restrict__ btWr, half_t* __restrict__ wet) {
  int m = blockIdx.y;
  const float* W;
  half_t* Bt;
  int K;
  if (m == 0)      { W = l0Wl; Bt = btL0l; K = 64; }
  else if (m == 1) { W = l0Wr; Bt = btL0r; K = 64; }
  else if (m == 2) { W = resW; Bt = btRes; K = 64; }
  else if (m < 8)  { int i = m - 3;  W = Wl + (size_t)i * 65536; Bt = btWl + (size_t)i * 65536; K = 256; }
  else if (m < 13) { int i = m - 8;  W = Wr + (size_t)i * 65536; Bt = btWr + (size_t)i * 65536; K = 256; }
  else             { int i = m - 13; W = We + (size_t)i * 8192;  Bt = wet + (size_t)i * 8192;  K = 32; }
  int i = blockIdx.x * 256 + threadIdx.x;
  if (i < K * 256) {
    int k = i >> 8, c = i & 255;
    Bt[(size_t)c * K + k] = (half_t)W[i];
  }
}

// ---------------- MFMA f16 GEMM body (shared, templated output type) ----------------
template <typename OutT>
DEV void gemm16_body(const float* __restrict__ A, const half_t* __restrict__ Bt,
                     const float* __restrict__ bias, OutT* __restrict__ C,
                     int M, int K, int bx, int bcol, int tid) {
  int w = tid >> 6, lane = tid & 63;
  int r16 = lane & 15, kg = lane >> 4;
  int arow = bx * 64 + w * 16 + r16;
  int arowc = arow < M ? arow : M - 1;
  f32x4 acc[4] = {};
  const int nks = K >> 5;
  const float* ap = A + (size_t)arowc * K + kg * 8;
  for (int ks = 0; ks < nks; ++ks) {
    float4 a0 = *(const float4*)(ap + ks * 32);
    float4 a1 = *(const float4*)(ap + ks * 32 + 4);
    half8_t af;
    af[0] = (half_t)a0.x; af[1] = (half_t)a0.y; af[2] = (half_t)a0.z; af[3] = (half_t)a0.w;
    af[4] = (half_t)a1.x; af[5] = (half_t)a1.y; af[6] = (half_t)a1.z; af[7] = (half_t)a1.w;
    int k0 = ks * 32 + kg * 8;
#pragma unroll
    for (int nt = 0; nt < 4; ++nt) {
      half8_t bf = *(const half8_t*)(Bt + (size_t)(bcol + nt * 16 + r16) * K + k0);
      acc[nt] = __builtin_amdgcn_mfma_f32_16x16x32_f16(af, bf, acc[nt], 0, 0, 0);
    }
  }
  int orow0 = bx * 64 + w * 16 + kg * 4;
#pragma unroll
  for (int nt = 0; nt < 4; ++nt) {
    int gcol = bcol + nt * 16 + r16;
    float bv = bias[gcol];
#pragma unroll
    for (int r = 0; r < 4; ++r) {
      int grow = orow0 + r;
      if (grow < M) C[(size_t)grow * 256 + gcol] = (OutT)(acc[nt][r] + bv);
    }
  }
}

__global__ __launch_bounds__(256) void k_gemm16(
    const float* __restrict__ A, const half_t* __restrict__ Bt,
    const float* __restrict__ bias, float* __restrict__ C, int M, int K) {
  gemm16_body<float>(A, Bt, bias, C, M, K, blockIdx.x, blockIdx.y * 64, threadIdx.x);
}

// xl (f16 out) and xr (f32 out) in one launch: by 0..3 -> xl, by 4..7 -> xr
__global__ __launch_bounds__(256) void k_gemm16x2(
    const float* __restrict__ A, const half_t* __restrict__ btl,
    const half_t* __restrict__ btr, const float* __restrict__ bl,
    const float* __restrict__ br, half_t* __restrict__ xl, float* __restrict__ xr,
    int M, int K) {
  if (blockIdx.y < 4)
    gemm16_body<half_t>(A, btl, bl, xl, M, K, blockIdx.x, blockIdx.y * 64, threadIdx.x);
  else
    gemm16_body<float>(A, btr, br, xr, M, K, blockIdx.x, (blockIdx.y - 4) * 64, threadIdx.x);
}

// ---------------- fused GATv2 layer ----------------
// ONE wave per node (no barrier). 4-edge pipelined groups: next group's src (s_load)
// + xl f16 gathers prefetched during current group's 4 independent GATEs.
// Index-clamped loads; pad edges zeroed via uniform validity (max-free softmax).
__global__ __launch_bounds__(256) void k_fused(
    const int* __restrict__ off, const int* __restrict__ src_csr,
    const half_t* __restrict__ ef_csr,
    const half_t* __restrict__ xl, const float* __restrict__ xr,
    const float* __restrict__ xprev,
    const half_t* __restrict__ Wet_l, const float* __restrict__ att_l,
    const float* __restrict__ convb, const float* __restrict__ lng,
    const float* __restrict__ lnb,
    float* __restrict__ xout, int N) {
  int lane = threadIdx.x & 63;
  int n = blockIdx.x * 4 + (threadIdx.x >> 6);
  if (n >= N) return;
  n = __builtin_amdgcn_readfirstlane(n);
  int h = lane >> 4, c0 = lane & 15;
  int ch0 = h * 64 + (c0 << 2);
  // w2[q][cc]: k-pair q of We column (ch0+cc), straight from f16 Wet ([256][32])
  half2_t w2[16][4];
#pragma unroll
  for (int cc = 0; cc < 4; ++cc) {
    const uint4* wp = (const uint4*)(Wet_l + (size_t)(ch0 + cc) * 32);
    uint4 q0 = wp[0], q1 = wp[1], q2 = wp[2], q3 = wp[3];
    w2[0][cc]  = __builtin_bit_cast(half2_t, q0.x);
    w2[1][cc]  = __builtin_bit_cast(half2_t, q0.y);
    w2[2][cc]  = __builtin_bit_cast(half2_t, q0.z);
    w2[3][cc]  = __builtin_bit_cast(half2_t, q0.w);
    w2[4][cc]  = __builtin_bit_cast(half2_t, q1.x);
    w2[5][cc]  = __builtin_bit_cast(half2_t, q1.y);
    w2[6][cc]  = __builtin_bit_cast(half2_t, q1.z);
    w2[7][cc]  = __builtin_bit_cast(half2_t, q1.w);
    w2[8][cc]  = __builtin_bit_cast(half2_t, q2.x);
    w2[9][cc]  = __builtin_bit_cast(half2_t, q2.y);
    w2[10][cc] = __builtin_bit_cast(half2_t, q2.z);
    w2[11][cc] = __builtin_bit_cast(half2_t, q2.w);
    w2[12][cc] = __builtin_bit_cast(half2_t, q3.x);
    w2[13][cc] = __builtin_bit_cast(half2_t, q3.y);
    w2[14][cc] = __builtin_bit_cast(half2_t, q3.z);
    w2[15][cc] = __builtin_bit_cast(half2_t, q3.w);
  }
  float4 att4 = *(const float4*)(att_l + ch0);
  float4 a06, a04;
  a06.x = 0.6f * att4.x; a06.y = 0.6f * att4.y; a06.z = 0.6f * att4.z; a06.w = 0.6f * att4.w;
  a04.x = 0.4f * att4.x; a04.y = 0.4f * att4.y; a04.z = 0.4f * att4.z; a04.w = 0.4f * att4.w;
  float4 xr4 = *(const float4*)(xr + (size_t)n * 256 + ch0);
  int o0 = off[n], o1 = off[n + 1];
  int deg = o1 - o0;
  float s = 0.f;
  float4 a4 = {0.f, 0.f, 0.f, 0.f};

#define LOADG(T0, S0, S1, S2, S3, X0, X1, X2, X3)                                    \
  {                                                                                  \
    int lim = o1 - 1;                                                                \
    int t0_ = (T0) < lim ? (T0) : lim;                                               \
    int t1_ = (T0) + 1 < lim ? (T0) + 1 : lim;                                       \
    int t2_ = (T0) + 2 < lim ? (T0) + 2 : lim;                                       \
    int t3_ = (T0) + 3 < lim ? (T0) + 3 : lim;                                       \
    S0 = src_csr[t0_]; S1 = src_csr[t1_]; S2 = src_csr[t2_]; S3 = src_csr[t3_];      \
    X0 = *(const half4_t*)(xl + (size_t)S0 * 256 + ch0);                             \
    X1 = *(const half4_t*)(xl + (size_t)S1 * 256 + ch0);                             \
    X2 = *(const half4_t*)(xl + (size_t)S2 * 256 + ch0);                             \
    X3 = *(const half4_t*)(xl + (size_t)S3 * 256 + ch0);                             \
  }

#define GATE(TT, XF, P)                                                              \
  {                                                                                  \
    const uint4* efq = (const uint4*)(ef_csr + (size_t)(TT) * 32);                   \
    uint4 fa = efq[0], fb = efq[1], fc = efq[2], fd = efq[3];                        \
    uint fw[16] = {fa.x, fa.y, fa.z, fa.w, fb.x, fb.y, fb.z, fb.w,                   \
                   fc.x, fc.y, fc.z, fc.w, fd.x, fd.y, fd.z, fd.w};                  \
    float e0 = (XF).x + xr4.x, e1 = (XF).y + xr4.y;                                  \
    float e2 = (XF).z + xr4.z, e3 = (XF).w + xr4.w;                                  \
    _Pragma("unroll") for (int q = 0; q < 16; ++q) {                                 \
      half2_t f = __builtin_bit_cast(half2_t, fw[q]);                                \
      e0 = __builtin_amdgcn_fdot2(f, w2[q][0], e0, false);                           \
      e1 = __builtin_amdgcn_fdot2(f, w2[q][1], e1, false);                           \
      e2 = __builtin_amdgcn_fdot2(f, w2[q][2], e2, false);                           \
      e3 = __builtin_amdgcn_fdot2(f, w2[q][3], e3, false);                           \
    }                                                                                \
    P = a06.x * e0 + a04.x * fabsf(e0);                                              \
    P += a06.y * e1 + a04.y * fabsf(e1);                                             \
    P += a06.z * e2 + a04.z * fabsf(e2);                                             \
    P += a06.w * e3 + a04.w * fabsf(e3);                                             \
  }

  if (deg > 0) {
    int s0, s1, s2, s3;
    half4_t xh0, xh1, xh2, xh3;
    LOADG(o0, s0, s1, s2, s3, xh0, xh1, xh2, xh3);
    for (int t0 = o0; t0 < o1; t0 += 4) {
      // prefetch next group (clamped; harmless waste on last iter)
      int ns0, ns1, ns2, ns3;
      half4_t nxh0, nxh1, nxh2, nxh3;
      LOADG(t0 + 4, ns0, ns1, ns2, ns3, nxh0, nxh1, nxh2, nxh3);
      int lim = o1 - 1;
      int t0_ = t0, t1_ = t0 + 1 < lim ? t0 + 1 : lim,
          t2_ = t0 + 2 < lim ? t0 + 2 : lim, t3_ = t0 + 3 < lim ? t0 + 3 : lim;
      float4 xf0, xf1, xf2, xf3;
      xf0.x = (float)xh0[0]; xf0.y = (float)xh0[1]; xf0.z = (float)xh0[2]; xf0.w = (float)xh0[3];
      xf1.x = (float)xh1[0]; xf1.y = (float)xh1[1]; xf1.z = (float)xh1[2]; xf1.w = (float)xh1[3];
      xf2.x = (float)xh2[0]; xf2.y = (float)xh2[1]; xf2.z = (float)xh2[2]; xf2.w = (float)xh2[3];
      xf3.x = (float)xh3[0]; xf3.y = (float)xh3[1]; xf3.z = (float)xh3[2]; xf3.w = (float)xh3[3];
      float p0, p1, p2, p3;
      GATE(t0_, xf0, p0);
      GATE(t1_, xf1, p1);
      GATE(t2_, xf2, p2);
      GATE(t3_, xf3, p3);
#pragma unroll
      for (int d = 1; d < 16; d <<= 1) {
        p0 += __shfl_xor(p0, d);
        p1 += __shfl_xor(p1, d);
        p2 += __shfl_xor(p2, d);
        p3 += __shfl_xor(p3, d);
      }
      float w0 = __expf(p0);
      float w1 = (t0 + 1 < o1) ? __expf(p1) : 0.f;
      float w2v = (t0 + 2 < o1) ? __expf(p2) : 0.f;
      float w3 = (t0 + 3 < o1) ? __expf(p3) : 0.f;
      s += (w0 + w1) + (w2v + w3);
      a4.x += w0 * xf0.x + w1 * xf1.x + w2v * xf2.x + w3 * xf3.x;
      a4.y += w0 * xf0.y + w1 * xf1.y + w2v * xf2.y + w3 * xf3.y;
      a4.z += w0 * xf0.z + w1 * xf1.z + w2v * xf2.z + w3 * xf3.z;
      a4.w += w0 * xf0.w + w1 * xf1.w + w2v * xf2.w + w3 * xf3.w;
      s0 = ns0; s1 = ns1; s2 = ns2; s3 = ns3;
      xh0 = nxh0; xh1 = nxh1; xh2 = nxh2; xh3 = nxh3;
    }
  }
#undef GATE
#undef LOADG

  float inv = (deg > 0) ? 1.f / s : 0.f;
  float4 cb4 = *(const float4*)(convb + ch0);
  float4 v4;
  v4.x = a4.x * inv + cb4.x;
  v4.y = a4.y * inv + cb4.y;
  v4.z = a4.z * inv + cb4.z;
  v4.w = a4.w * inv + cb4.w;
  float ssum = v4.x + v4.y + v4.z + v4.w;
  float ssq = v4.x * v4.x + v4.y * v4.y + v4.z * v4.z + v4.w * v4.w;
#pragma unroll
  for (int d = 1; d < 64; d <<= 1) {
    ssum += __shfl_xor(ssum, d);
    ssq += __shfl_xor(ssq, d);
  }
  float mu = ssum * (1.0f / 256.0f);
  float var = ssq * (1.0f / 256.0f) - mu * mu;
  float rstd = rsqrtf(var + 1e-5f);
  float4 g4 = *(const float4*)(lng + ch0);
  float4 b4 = *(const float4*)(lnb + ch0);
  float4 xp4 = *(const float4*)(xprev + (size_t)n * 256 + ch0);
  float4 out4;
  out4.x = fmaxf((v4.x - mu) * rstd * g4.x + b4.x, 0.f) + xp4.x;
  out4.y = fmaxf((v4.y - mu) * rstd * g4.y + b4.y, 0.f) + xp4.y;
  out4.z = fmaxf((v4.z - mu) * rstd * g4.z + b4.z, 0.f) + xp4.z;
  out4.w = fmaxf((v4.w - mu) * rstd * g4.w + b4.w, 0.f) + xp4.w;
  *(float4*)(xout + (size_t)n * 256 + ch0) = out4;
}

// ---------------- output projection ----------------
__global__ __launch_bounds__(256) void k_out(
    const float* __restrict__ x, const float* __restrict__ W1, const float* __restrict__ b1,
    const float* __restrict__ W2, const float* __restrict__ b2,
    float* __restrict__ out, int N) {
  __shared__ float sW1[256 * 64];  // 64 KB
  for (int i = threadIdx.x; i < 256 * 64; i += 256) sW1[i] = W1[i];
  __syncthreads();
  int lane = threadIdx.x & 63;
  int wv = threadIdx.x >> 6;
  for (int n = blockIdx.x * 4 + wv; n < N; n += gridDim.x * 4) {
    const float* xrow = x + (size_t)n * 256;
    float h = b1[lane];
    for (int k = 0; k < 256; ++k) h += xrow[k] * sW1[k * 64 + lane];
    h = fmaxf(h, 0.f);
    float y[5];
#pragma unroll
    for (int o = 0; o < 5; ++o) {
      float p = h * W2[lane * 5 + o];
#pragma unroll
      for (int d = 1; d < 64; d <<= 1) p += __shfl_xor(p, d);
      y[o] = p;
    }
    if (lane == 0) {
#pragma unroll
      for (int o = 0; o < 5; ++o) out[(size_t)n * 5 + o] = y[o] + b2[o];
    }
  }
}

extern "C" void kernel_launch(void* const* d_in, const int* in_sizes, int n_in,
                              void* d_out, int out_size, void* d_ws, size_t ws_size,
                              hipStream_t stream) {
  const float* nf      = (const float*)d_in[0];
  const float* gf      = (const float*)d_in[1];
  const int*   eidx    = (const int*)d_in[2];
  const float* pos     = (const float*)d_in[3];
  const float* ip_W    = (const float*)d_in[4];
  const float* ip_b    = (const float*)d_in[5];
  const float* film_gW = (const float*)d_in[6];
  const float* film_gb = (const float*)d_in[7];
  const float* film_bW = (const float*)d_in[8];
  const float* film_bb = (const float*)d_in[9];
  const float* ee_W1   = (const float*)d_in[10];
  const float* ee_b1   = (const float*)d_in[11];
  const float* ee_W2   = (const float*)d_in[12];
  const float* ee_b2   = (const float*)d_in[13];
  const float* res_W   = (const float*)d_in[14];
  const float* res_b   = (const float*)d_in[15];
  const float* l0_Wl   = (const float*)d_in[16];
  const float* l0_bl   = (const float*)d_in[17];
  const float* l0_Wr   = (const float*)d_in[18];
  const float* l0_br   = (const float*)d_in[19];
  const float* Wl      = (const float*)d_in[20];
  const float* bl      = (const float*)d_in[21];
  const float* Wr      = (const float*)d_in[22];
  const float* br      = (const float*)d_in[23];
  const float* We      = (const float*)d_in[24];
  const float* att     = (const float*)d_in[25];
  const float* conv_b  = (const float*)d_in[26];
  const float* ln_g    = (const float*)d_in[27];
  const float* ln_b    = (const float*)d_in[28];
  const float* op_W1   = (const float*)d_in[29];
  const float* op_b1   = (const float*)d_in[30];
  const float* op_W2   = (const float*)d_in[31];
  const float* op_b2   = (const float*)d_in[32];

  const int N = in_sizes[0] / 5;
  const int E = in_sizes[2] / 2;
  const int* src = eidx;
  const int* dst = eidx + E;

  float* ws = (float*)d_ws;
  size_t o = 0;
  auto alloc = [&](size_t nflt) {
    float* p = ws + o;
    o += (nflt + 63) & ~(size_t)63;
    return p;
  };
  float* gb      = alloc(128);
  float* x64     = alloc((size_t)N * 64);
  half_t* ef_csr = (half_t*)alloc((size_t)E * 16);  // E*32 halfs
  int*   src_csr = (int*)alloc((size_t)E);
  int*   cnt     = (int*)alloc(2 * (size_t)N);
  int*   cur     = cnt + N;
  int*   csroff  = (int*)alloc((size_t)N + 1);
  int*   csreid  = (int*)alloc((size_t)E);
  int*   bsum    = (int*)alloc(256);
  half_t* xl     = (half_t*)alloc((size_t)N * 128);  // N*256 halfs
  float* xr      = alloc((size_t)N * 256);
  float* xA      = alloc((size_t)N * 256);
  float* xB      = alloc((size_t)N * 256);
  float* xp0     = alloc((size_t)N * 256);
  half_t* btL0l  = (half_t*)alloc(256 * 64 / 2);
  half_t* btL0r  = (half_t*)alloc(256 * 64 / 2);
  half_t* btRes  = (half_t*)alloc(256 * 64 / 2);
  half_t* btWl   = (half_t*)alloc(5 * 256 * 256 / 2);
  half_t* btWr   = (half_t*)alloc(5 * 256 * 256 / 2);
  half_t* wet    = (half_t*)alloc(6 * 256 * 32 / 2);  // We^T per layer: [256][32] f16

  (void)ws_size; (void)n_in; (void)out_size;

  hipMemsetAsync(cnt, 0, 2 * (size_t)N * sizeof(int), stream);

  const int nbN = (N + 255) / 256;
  k_film<<<1, 64, 0, stream>>>(gf, film_gW, film_gb, film_bW, film_bb, gb);
  k_input<<<(N + 3) / 4, 256, 0, stream>>>(nf, ip_W, ip_b, gb, x64, N);
  k_count<<<(E + 255) / 256, 256, 0, stream>>>(dst, cnt, E);
  k_scan1<<<nbN, 256, 0, stream>>>(cnt, csroff, bsum, N);
  k_scan2<<<1, 256, 0, stream>>>(bsum, nbN);
  k_scan3<<<nbN, 256, 0, stream>>>(csroff, bsum, N, E);
  k_scatter<<<(E + 255) / 256, 256, 0, stream>>>(dst, csroff, cur, csreid, E);
  k_edgefeat<<<(E + 255) / 256, 256, 0, stream>>>(pos, src, dst, csreid,
      ee_W1, ee_b1, ee_W2, ee_b2, ef_csr, src_csr, E);

  k_prepAll<<<dim3(256, 19), 256, 0, stream>>>(l0_Wl, l0_Wr, res_W, Wl, Wr, We,
                                               btL0l, btL0r, btRes, btWl, btWr, wet);

  const float* xin = x64;
  for (int layer = 0; layer < 6; ++layer) {
    const int K = (layer == 0) ? 64 : 256;
    const half_t* btl = (layer == 0) ? btL0l : (btWl + (size_t)(layer - 1) * 256 * 256);
    const half_t* btr = (layer == 0) ? btL0r : (btWr + (size_t)(layer - 1) * 256 * 256);
    const float* bl_p = (layer == 0) ? l0_bl : (bl + (size_t)(layer - 1) * 256);
    const float* br_p = (layer == 0) ? l0_br : (br + (size_t)(layer - 1) * 256);

    dim3 gg2((N + 63) / 64, 8);
    k_gemm16x2<<<gg2, 256, 0, stream>>>(xin, btl, btr, bl_p, br_p, xl, xr, N, K);

    const float* prev;
    if (layer == 0) {
      dim3 gg((N + 63) / 64, 4);
      k_gemm16<<<gg, 256, 0, stream>>>(xin, btRes, res_b, xp0, N, 64);
      prev = xp0;
    } else {
      prev = xin;
    }

    float* xout = (layer & 1) ? xB : xA;
    k_fused<<<(N + 3) / 4, 256, 0, stream>>>(
        csroff, src_csr, ef_csr, xl, xr, prev,
        wet + (size_t)layer * 256 * 32, att + (size_t)layer * 256,
        conv_b + (size_t)layer * 256, ln_g + (size_t)layer * 256, ln_b + (size_t)layer * 256,
        xout, N);
    xin = xout;
  }

  k_out<<<512, 256, 0, stream>>>(xin, op_W1, op_b1, op_W2, op_b2, (float*)d_out, N);
}

// Round 10
// 987.072 us; speedup vs baseline: 1.8389x; 1.2168x over previous
//
#include <hip/hip_runtime.h>
#include <cmath>

#define DEV static __device__ __forceinline__

typedef _Float16 half_t;
typedef _Float16 half2_t __attribute__((ext_vector_type(2)));
typedef _Float16 half4_t __attribute__((ext_vector_type(4)));
typedef _Float16 half8_t __attribute__((ext_vector_type(8)));
typedef float f32x4 __attribute__((ext_vector_type(4)));

// ---------------- input projection + FiLM (film inlined per-thread) ----------------
__global__ __launch_bounds__(256) void k_input(
    const float* __restrict__ nf, const float* __restrict__ ipW,
    const float* __restrict__ ipb, const float* __restrict__ gf,
    const float* __restrict__ gW, const float* __restrict__ gb,
    const float* __restrict__ bW, const float* __restrict__ bb,
    float* __restrict__ x64, int N) {
  int lane = threadIdx.x & 63;
  int n = blockIdx.x * 4 + (threadIdx.x >> 6);
  if (n >= N) return;
  float g = gb[lane], b = bb[lane];
  for (int k = 0; k < 128; ++k) {
    float v = gf[k];
    g += v * gW[k * 64 + lane];
    b += v * bW[k * 64 + lane];
  }
  float gamma1 = 1.0f + g;
  const float* row = nf + (size_t)n * 5;
  float acc = ipb[lane];
#pragma unroll
  for (int k = 0; k < 5; ++k) acc += row[k] * ipW[k * 64 + lane];
  acc = fmaxf(acc, 0.f);
  x64[(size_t)n * 64 + lane] = acc * gamma1 + b;
}

// ---------------- CSR build ----------------
__global__ void k_count(const int* __restrict__ dst, int* __restrict__ cnt, int E) {
  int e = blockIdx.x * 256 + threadIdx.x;
  if (e < E) atomicAdd(&cnt[dst[e]], 1);
}

// single-kernel offsets: block-local scan + atomic global base (order-independent;
// downstream only needs (start, deg) pairs, not a monotone prefix sum)
__global__ void k_offsets(const int* __restrict__ cnt, int* __restrict__ start,
                          int* __restrict__ cursor, int N) {
  __shared__ int s[256];
  __shared__ int sbase;
  int tid = threadIdx.x;
  int i = blockIdx.x * 256 + tid;
  int v = (i < N) ? cnt[i] : 0;
  s[tid] = v;
  __syncthreads();
  int x = v;
  for (int d = 1; d < 256; d <<= 1) {
    int t = (tid >= d) ? s[tid - d] : 0;
    __syncthreads();
    x += t;
    s[tid] = x;
    __syncthreads();
  }
  if (tid == 255) sbase = atomicAdd(cursor, x);
  __syncthreads();
  if (i < N) start[i] = sbase + x - v;
}

// ---------------- edge encoder + scatter fused: compute CSR position directly ----------------
__global__ __launch_bounds__(256) void k_edgefeat(
    const float* __restrict__ pos, const int* __restrict__ src, const int* __restrict__ dst,
    const int* __restrict__ start, int* __restrict__ cur,
    const float* __restrict__ W1, const float* __restrict__ b1,
    const float* __restrict__ W2, const float* __restrict__ b2,
    half_t* __restrict__ ef_csr, int* __restrict__ src_csr, int E) {
  __shared__ float sW1[160], sb1[32], sW2[1024], sb2[32];
  for (int i = threadIdx.x; i < 160; i += 256) sW1[i] = W1[i];
  for (int i = threadIdx.x; i < 1024; i += 256) sW2[i] = W2[i];
  if (threadIdx.x < 32) { sb1[threadIdx.x] = b1[threadIdx.x]; sb2[threadIdx.x] = b2[threadIdx.x]; }
  __syncthreads();
  int e = blockIdx.x * 256 + threadIdx.x;
  if (e >= E) return;
  int s = src[e], d = dst[e];
  int p = atomicAdd(&cur[d], 1);
  int t = start[d] + p;
  src_csr[t] = s;
  float dx = pos[d * 3 + 0] - pos[s * 3 + 0];
  float dy = pos[d * 3 + 1] - pos[s * 3 + 1];
  float dz = pos[d * 3 + 2] - pos[s * 3 + 2];
  float dist = sqrtf(dx * dx + dy * dy + dz * dz);
  dist = fmaxf(dist, 1e-6f);
  float inv = 1.f / dist;
  float attr[5] = {dx * inv, dy * inv, dz * inv, dist, logf(dist)};
  float h[32];
#pragma unroll
  for (int j = 0; j < 32; ++j) {
    float a = sb1[j];
#pragma unroll
    for (int k = 0; k < 5; ++k) a += attr[k] * sW1[k * 32 + j];
    h[j] = fmaxf(a, 0.f);
  }
  half_t hv[32];
#pragma unroll 4
  for (int j = 0; j < 32; ++j) {
    float a = sb2[j];
#pragma unroll
    for (int k = 0; k < 32; ++k) a += h[k] * sW2[k * 32 + j];
    hv[j] = (half_t)a;
  }
  uint4* ov = (uint4*)(ef_csr + (size_t)t * 32);
  const uint4* iv = (const uint4*)hv;
  ov[0] = iv[0]; ov[1] = iv[1]; ov[2] = iv[2]; ov[3] = iv[3];
}

// ---------------- batched weight prep: contiguous OUTPUT (reads scattered, L2-hot) ----------------
__global__ __launch_bounds__(256) void k_prepAll(
    const float* __restrict__ l0Wl, const float* __restrict__ l0Wr,
    const float* __restrict__ resW, const float* __restrict__ Wl,
    const float* __restrict__ Wr, const float* __restrict__ We,
    half_t* __restrict__ btL0l, half_t* __restrict__ btL0r, half_t* __restrict__ btRes,
    half_t* __restrict__ btWl, half_t* __restrict__ btWr, half_t* __restrict__ wet) {
  int m = blockIdx.y;
  const float* W;
  half_t* Bt;
  int K, sh;
  if (m == 0)      { W = l0Wl; Bt = btL0l; K = 64; sh = 6; }
  else if (m == 1) { W = l0Wr; Bt = btL0r; K = 64; sh = 6; }
  else if (m == 2) { W = resW; Bt = btRes; K = 64; sh = 6; }
  else if (m < 8)  { int i = m - 3;  W = Wl + (size_t)i * 65536; Bt = btWl + (size_t)i * 65536; K = 256; sh = 8; }
  else if (m < 13) { int i = m - 8;  W = Wr + (size_t)i * 65536; Bt = btWr + (size_t)i * 65536; K = 256; sh = 8; }
  else             { int i = m - 13; W = We + (size_t)i * 8192;  Bt = wet + (size_t)i * 8192;  K = 32; sh = 5; }
  int j = blockIdx.x * 256 + threadIdx.x;
  if (j < K * 256) {
    int c = j >> sh, k = j & (K - 1);
    Bt[j] = (half_t)W[k * 256 + c];  // Bt[c*K+k]
  }
}

// ---------------- MFMA f16 GEMM, full 256-col per block: A read once ----------------
template <typename OutT, int NKS>
DEV void gemm_wide(const float* __restrict__ A, const half_t* __restrict__ Bt,
                   const float* __restrict__ bias, OutT* __restrict__ C,
                   int M, int bx, int tid) {
  constexpr int K = NKS * 32;
  int w = tid >> 6, lane = tid & 63;
  int r16 = lane & 15, kg = lane >> 4;
  int arow = bx * 64 + w * 16 + r16;
  int arowc = arow < M ? arow : M - 1;
  const float* ap = A + (size_t)arowc * K + kg * 8;
  half8_t af[NKS];
#pragma unroll
  for (int ks = 0; ks < NKS; ++ks) {
    float4 a0 = *(const float4*)(ap + ks * 32);
    float4 a1 = *(const float4*)(ap + ks * 32 + 4);
    af[ks][0] = (half_t)a0.x; af[ks][1] = (half_t)a0.y;
    af[ks][2] = (half_t)a0.z; af[ks][3] = (half_t)a0.w;
    af[ks][4] = (half_t)a1.x; af[ks][5] = (half_t)a1.y;
    af[ks][6] = (half_t)a1.z; af[ks][7] = (half_t)a1.w;
  }
  int orow0 = bx * 64 + w * 16 + kg * 4;
#pragma unroll
  for (int c4 = 0; c4 < 4; ++c4) {
    f32x4 acc[4] = {};
#pragma unroll
    for (int ks = 0; ks < NKS; ++ks) {
#pragma unroll
      for (int nt = 0; nt < 4; ++nt) {
        half8_t bf = *(const half8_t*)(Bt + (size_t)(c4 * 64 + nt * 16 + r16) * K + ks * 32 + kg * 8);
        acc[nt] = __builtin_amdgcn_mfma_f32_16x16x32_f16(af[ks], bf, acc[nt], 0, 0, 0);
      }
    }
#pragma unroll
    for (int nt = 0; nt < 4; ++nt) {
      int gcol = c4 * 64 + nt * 16 + r16;
      float bv = bias[gcol];
#pragma unroll
      for (int r = 0; r < 4; ++r) {
        int grow = orow0 + r;
        if (grow < M) C[(size_t)grow * 256 + gcol] = (OutT)(acc[nt][r] + bv);
      }
    }
  }
}

// layers 1..5 (K=256): y=0 -> xl (f16), y=1 -> xr (f32)
__global__ __launch_bounds__(256) void k_gemmL(
    const float* __restrict__ A, const half_t* __restrict__ btl,
    const half_t* __restrict__ btr, const float* __restrict__ bl,
    const float* __restrict__ br, half_t* __restrict__ xl, float* __restrict__ xr, int M) {
  if (blockIdx.y == 0)
    gemm_wide<half_t, 8>(A, btl, bl, xl, M, blockIdx.x, threadIdx.x);
  else
    gemm_wide<float, 8>(A, btr, br, xr, M, blockIdx.x, threadIdx.x);
}

// layer 0 (K=64): y=0 -> xl, y=1 -> xr, y=2 -> res
__global__ __launch_bounds__(256) void k_gemmL0(
    const float* __restrict__ A, const half_t* __restrict__ btl,
    const half_t* __restrict__ btr, const half_t* __restrict__ btres,
    const float* __restrict__ bl, const float* __restrict__ br,
    const float* __restrict__ bres,
    half_t* __restrict__ xl, float* __restrict__ xr, float* __restrict__ xp0, int M) {
  if (blockIdx.y == 0)
    gemm_wide<half_t, 2>(A, btl, bl, xl, M, blockIdx.x, threadIdx.x);
  else if (blockIdx.y == 1)
    gemm_wide<float, 2>(A, btr, br, xr, M, blockIdx.x, threadIdx.x);
  else
    gemm_wide<float, 2>(A, btres, bres, xp0, M, blockIdx.x, threadIdx.x);
}

// ---------------- fused GATv2 layer: ONE wave per node, block = 64 ----------------
__global__ __launch_bounds__(64) void k_fused(
    const int* __restrict__ start, const int* __restrict__ cnt,
    const int* __restrict__ src_csr, const half_t* __restrict__ ef_csr,
    const half_t* __restrict__ xl, const float* __restrict__ xr,
    const float* __restrict__ xprev,
    const half_t* __restrict__ Wet_l, const float* __restrict__ att_l,
    const float* __restrict__ convb, const float* __restrict__ lng,
    const float* __restrict__ lnb,
    float* __restrict__ xout) {
  int lane = threadIdx.x;
  int n = blockIdx.x;
  int h = lane >> 4, c0 = lane & 15;
  int ch0 = h * 64 + (c0 << 2);
  half2_t w2[16][4];
#pragma unroll
  for (int cc = 0; cc < 4; ++cc) {
    const uint4* wp = (const uint4*)(Wet_l + (size_t)(ch0 + cc) * 32);
    uint4 q0 = wp[0], q1 = wp[1], q2 = wp[2], q3 = wp[3];
    w2[0][cc]  = __builtin_bit_cast(half2_t, q0.x);
    w2[1][cc]  = __builtin_bit_cast(half2_t, q0.y);
    w2[2][cc]  = __builtin_bit_cast(half2_t, q0.z);
    w2[3][cc]  = __builtin_bit_cast(half2_t, q0.w);
    w2[4][cc]  = __builtin_bit_cast(half2_t, q1.x);
    w2[5][cc]  = __builtin_bit_cast(half2_t, q1.y);
    w2[6][cc]  = __builtin_bit_cast(half2_t, q1.z);
    w2[7][cc]  = __builtin_bit_cast(half2_t, q1.w);
    w2[8][cc]  = __builtin_bit_cast(half2_t, q2.x);
    w2[9][cc]  = __builtin_bit_cast(half2_t, q2.y);
    w2[10][cc] = __builtin_bit_cast(half2_t, q2.z);
    w2[11][cc] = __builtin_bit_cast(half2_t, q2.w);
    w2[12][cc] = __builtin_bit_cast(half2_t, q3.x);
    w2[13][cc] = __builtin_bit_cast(half2_t, q3.y);
    w2[14][cc] = __builtin_bit_cast(half2_t, q3.z);
    w2[15][cc] = __builtin_bit_cast(half2_t, q3.w);
  }
  float4 att4 = *(const float4*)(att_l + ch0);
  float4 a06, a04;
  a06.x = 0.6f * att4.x; a06.y = 0.6f * att4.y; a06.z = 0.6f * att4.z; a06.w = 0.6f * att4.w;
  a04.x = 0.4f * att4.x; a04.y = 0.4f * att4.y; a04.z = 0.4f * att4.z; a04.w = 0.4f * att4.w;
  float4 xr4 = *(const float4*)(xr + (size_t)n * 256 + ch0);
  int o0 = start[n];
  int deg = cnt[n];
  int o1 = o0 + deg;
  float s = 0.f;
  float4 a4 = {0.f, 0.f, 0.f, 0.f};

#define LOADG(T0, X0, X1, X2, X3)                                                    \
  {                                                                                  \
    int lim = o1 - 1;                                                                \
    int t0_ = (T0) < lim ? (T0) : lim;                                               \
    int t1_ = (T0) + 1 < lim ? (T0) + 1 : lim;                                       \
    int t2_ = (T0) + 2 < lim ? (T0) + 2 : lim;                                       \
    int t3_ = (T0) + 3 < lim ? (T0) + 3 : lim;                                       \
    int S0 = src_csr[t0_], S1 = src_csr[t1_], S2 = src_csr[t2_], S3 = src_csr[t3_];  \
    X0 = *(const half4_t*)(xl + (size_t)S0 * 256 + ch0);                             \
    X1 = *(const half4_t*)(xl + (size_t)S1 * 256 + ch0);                             \
    X2 = *(const half4_t*)(xl + (size_t)S2 * 256 + ch0);                             \
    X3 = *(const half4_t*)(xl + (size_t)S3 * 256 + ch0);                             \
  }

#define GATE(TT, XF, P)                                                              \
  {                                                                                  \
    const uint4* efq = (const uint4*)(ef_csr + (size_t)(TT) * 32);                   \
    uint4 fa = efq[0], fb = efq[1], fc = efq[2], fd = efq[3];                        \
    uint fw[16] = {fa.x, fa.y, fa.z, fa.w, fb.x, fb.y, fb.z, fb.w,                   \
                   fc.x, fc.y, fc.z, fc.w, fd.x, fd.y, fd.z, fd.w};                  \
    float e0 = (XF).x + xr4.x, e1 = (XF).y + xr4.y;                                  \
    float e2 = (XF).z + xr4.z, e3 = (XF).w + xr4.w;                                  \
    _Pragma("unroll") for (int q = 0; q < 16; ++q) {                                 \
      half2_t f = __builtin_bit_cast(half2_t, fw[q]);                                \
      e0 = __builtin_amdgcn_fdot2(f, w2[q][0], e0, false);                           \
      e1 = __builtin_amdgcn_fdot2(f, w2[q][1], e1, false);                           \
      e2 = __builtin_amdgcn_fdot2(f, w2[q][2], e2, false);                           \
      e3 = __builtin_amdgcn_fdot2(f, w2[q][3], e3, false);                           \
    }                                                                                \
    P = a06.x * e0 + a04.x * fabsf(e0);                                              \
    P += a06.y * e1 + a04.y * fabsf(e1);                                             \
    P += a06.z * e2 + a04.z * fabsf(e2);                                             \
    P += a06.w * e3 + a04.w * fabsf(e3);                                             \
  }

  if (deg > 0) {
    half4_t xh0, xh1, xh2, xh3;
    LOADG(o0, xh0, xh1, xh2, xh3);
    for (int t0 = o0; t0 < o1; t0 += 4) {
      half4_t nxh0, nxh1, nxh2, nxh3;
      LOADG(t0 + 4, nxh0, nxh1, nxh2, nxh3);
      int lim = o1 - 1;
      int t0_ = t0, t1_ = t0 + 1 < lim ? t0 + 1 : lim,
          t2_ = t0 + 2 < lim ? t0 + 2 : lim, t3_ = t0 + 3 < lim ? t0 + 3 : lim;
      float4 xf0, xf1, xf2, xf3;
      xf0.x = (float)xh0[0]; xf0.y = (float)xh0[1]; xf0.z = (float)xh0[2]; xf0.w = (float)xh0[3];
      xf1.x = (float)xh1[0]; xf1.y = (float)xh1[1]; xf1.z = (float)xh1[2]; xf1.w = (float)xh1[3];
      xf2.x = (float)xh2[0]; xf2.y = (float)xh2[1]; xf2.z = (float)xh2[2]; xf2.w = (float)xh2[3];
      xf3.x = (float)xh3[0]; xf3.y = (float)xh3[1]; xf3.z = (float)xh3[2]; xf3.w = (float)xh3[3];
      float p0, p1, p2, p3;
      GATE(t0_, xf0, p0);
      GATE(t1_, xf1, p1);
      GATE(t2_, xf2, p2);
      GATE(t3_, xf3, p3);
#pragma unroll
      for (int d = 1; d < 16; d <<= 1) {
        p0 += __shfl_xor(p0, d);
        p1 += __shfl_xor(p1, d);
        p2 += __shfl_xor(p2, d);
        p3 += __shfl_xor(p3, d);
      }
      float w0 = __expf(p0);
      float w1 = (t0 + 1 < o1) ? __expf(p1) : 0.f;
      float w2v = (t0 + 2 < o1) ? __expf(p2) : 0.f;
      float w3 = (t0 + 3 < o1) ? __expf(p3) : 0.f;
      s += (w0 + w1) + (w2v + w3);
      a4.x += w0 * xf0.x + w1 * xf1.x + w2v * xf2.x + w3 * xf3.x;
      a4.y += w0 * xf0.y + w1 * xf1.y + w2v * xf2.y + w3 * xf3.y;
      a4.z += w0 * xf0.z + w1 * xf1.z + w2v * xf2.z + w3 * xf3.z;
      a4.w += w0 * xf0.w + w1 * xf1.w + w2v * xf2.w + w3 * xf3.w;
      xh0 = nxh0; xh1 = nxh1; xh2 = nxh2; xh3 = nxh3;
    }
  }
#undef GATE
#undef LOADG

  float inv = (deg > 0) ? 1.f / s : 0.f;
  float4 cb4 = *(const float4*)(convb + ch0);
  float4 v4;
  v4.x = a4.x * inv + cb4.x;
  v4.y = a4.y * inv + cb4.y;
  v4.z = a4.z * inv + cb4.z;
  v4.w = a4.w * inv + cb4.w;
  float ssum = v4.x + v4.y + v4.z + v4.w;
  float ssq = v4.x * v4.x + v4.y * v4.y + v4.z * v4.z + v4.w * v4.w;
#pragma unroll
  for (int d = 1; d < 64; d <<= 1) {
    ssum += __shfl_xor(ssum, d);
    ssq += __shfl_xor(ssq, d);
  }
  float mu = ssum * (1.0f / 256.0f);
  float var = ssq * (1.0f / 256.0f) - mu * mu;
  float rstd = rsqrtf(var + 1e-5f);
  float4 g4 = *(const float4*)(lng + ch0);
  float4 b4 = *(const float4*)(lnb + ch0);
  float4 xp4 = *(const float4*)(xprev + (size_t)n * 256 + ch0);
  float4 out4;
  out4.x = fmaxf((v4.x - mu) * rstd * g4.x + b4.x, 0.f) + xp4.x;
  out4.y = fmaxf((v4.y - mu) * rstd * g4.y + b4.y, 0.f) + xp4.y;
  out4.z = fmaxf((v4.z - mu) * rstd * g4.z + b4.z, 0.f) + xp4.z;
  out4.w = fmaxf((v4.w - mu) * rstd * g4.w + b4.w, 0.f) + xp4.w;
  *(float4*)(xout + (size_t)n * 256 + ch0) = out4;
}

// ---------------- output projection ----------------
__global__ __launch_bounds__(256) void k_out(
    const float* __restrict__ x, const float* __restrict__ W1, const float* __restrict__ b1,
    const float* __restrict__ W2, const float* __restrict__ b2,
    float* __restrict__ out, int N) {
  __shared__ float sW1[256 * 64];  // 64 KB
  for (int i = threadIdx.x; i < 256 * 64; i += 256) sW1[i] = W1[i];
  __syncthreads();
  int lane = threadIdx.x & 63;
  int wv = threadIdx.x >> 6;
  for (int n = blockIdx.x * 4 + wv; n < N; n += gridDim.x * 4) {
    const float* xrow = x + (size_t)n * 256;
    float h = b1[lane];
    for (int k = 0; k < 256; ++k) h += xrow[k] * sW1[k * 64 + lane];
    h = fmaxf(h, 0.f);
    float y[5];
#pragma unroll
    for (int o = 0; o < 5; ++o) {
      float p = h * W2[lane * 5 + o];
#pragma unroll
      for (int d = 1; d < 64; d <<= 1) p += __shfl_xor(p, d);
      y[o] = p;
    }
    if (lane == 0) {
#pragma unroll
      for (int o = 0; o < 5; ++o) out[(size_t)n * 5 + o] = y[o] + b2[o];
    }
  }
}

extern "C" void kernel_launch(void* const* d_in, const int* in_sizes, int n_in,
                              void* d_out, int out_size, void* d_ws, size_t ws_size,
                              hipStream_t stream) {
  const float* nf      = (const float*)d_in[0];
  const float* gf      = (const float*)d_in[1];
  const int*   eidx    = (const int*)d_in[2];
  const float* pos     = (const float*)d_in[3];
  const float* ip_W    = (const float*)d_in[4];
  const float* ip_b    = (const float*)d_in[5];
  const float* film_gW = (const float*)d_in[6];
  const float* film_gb = (const float*)d_in[7];
  const float* film_bW = (const float*)d_in[8];
  const float* film_bb = (const float*)d_in[9];
  const float* ee_W1   = (const float*)d_in[10];
  const float* ee_b1   = (const float*)d_in[11];
  const float* ee_W2   = (const float*)d_in[12];
  const float* ee_b2   = (const float*)d_in[13];
  const float* res_W   = (const float*)d_in[14];
  const float* res_b   = (const float*)d_in[15];
  const float* l0_Wl   = (const float*)d_in[16];
  const float* l0_bl   = (const float*)d_in[17];
  const float* l0_Wr   = (const float*)d_in[18];
  const float* l0_br   = (const float*)d_in[19];
  const float* Wl      = (const float*)d_in[20];
  const float* bl      = (const float*)d_in[21];
  const float* Wr      = (const float*)d_in[22];
  const float* br      = (const float*)d_in[23];
  const float* We      = (const float*)d_in[24];
  const float* att     = (const float*)d_in[25];
  const float* conv_b  = (const float*)d_in[26];
  const float* ln_g    = (const float*)d_in[27];
  const float* ln_b    = (const float*)d_in[28];
  const float* op_W1   = (const float*)d_in[29];
  const float* op_b1   = (const float*)d_in[30];
  const float* op_W2   = (const float*)d_in[31];
  const float* op_b2   = (const float*)d_in[32];

  const int N = in_sizes[0] / 5;
  const int E = in_sizes[2] / 2;
  const int* src = eidx;
  const int* dst = eidx + E;

  float* ws = (float*)d_ws;
  size_t o = 0;
  auto alloc = [&](size_t nflt) {
    float* p = ws + o;
    o += (nflt + 63) & ~(size_t)63;
    return p;
  };
  float* x64     = alloc((size_t)N * 64);
  half_t* ef_csr = (half_t*)alloc((size_t)E * 16);  // E*32 halfs
  int*   src_csr = (int*)alloc((size_t)E);
  int*   cnt     = (int*)alloc(2 * (size_t)N + 64);  // [cnt N][cur N][cursor]
  int*   cur     = cnt + N;
  int*   cursor  = cnt + 2 * N;
  int*   csrst   = (int*)alloc((size_t)N);
  half_t* xl     = (half_t*)alloc((size_t)N * 128);  // N*256 halfs
  float* xr      = alloc((size_t)N * 256);
  float* xA      = alloc((size_t)N * 256);
  float* xB      = alloc((size_t)N * 256);
  float* xp0     = alloc((size_t)N * 256);
  half_t* btL0l  = (half_t*)alloc(256 * 64 / 2);
  half_t* btL0r  = (half_t*)alloc(256 * 64 / 2);
  half_t* btRes  = (half_t*)alloc(256 * 64 / 2);
  half_t* btWl   = (half_t*)alloc(5 * 256 * 256 / 2);
  half_t* btWr   = (half_t*)alloc(5 * 256 * 256 / 2);
  half_t* wet    = (half_t*)alloc(6 * 256 * 32 / 2);  // We^T per layer: [256][32] f16

  (void)ws_size; (void)n_in; (void)out_size;

  hipMemsetAsync(cnt, 0, (2 * (size_t)N + 64) * sizeof(int), stream);

  const int nbN = (N + 255) / 256;
  k_input<<<(N + 3) / 4, 256, 0, stream>>>(nf, ip_W, ip_b, gf,
      film_gW, film_gb, film_bW, film_bb, x64, N);
  k_count<<<(E + 255) / 256, 256, 0, stream>>>(dst, cnt, E);
  k_offsets<<<nbN, 256, 0, stream>>>(cnt, csrst, cursor, N);
  k_edgefeat<<<(E + 255) / 256, 256, 0, stream>>>(pos, src, dst, csrst, cur,
      ee_W1, ee_b1, ee_W2, ee_b2, ef_csr, src_csr, E);
  k_prepAll<<<dim3(256, 19), 256, 0, stream>>>(l0_Wl, l0_Wr, res_W, Wl, Wr, We,
                                               btL0l, btL0r, btRes, btWl, btWr, wet);

  const int gx = (N + 63) / 64;
  const float* xin = x64;
  for (int layer = 0; layer < 6; ++layer) {
    const float* prev;
    if (layer == 0) {
      k_gemmL0<<<dim3(gx, 3), 256, 0, stream>>>(xin, btL0l, btL0r, btRes,
                                                l0_bl, l0_br, res_b, xl, xr, xp0, N);
      prev = xp0;
    } else {
      k_gemmL<<<dim3(gx, 2), 256, 0, stream>>>(
          xin, btWl + (size_t)(layer - 1) * 65536, btWr + (size_t)(layer - 1) * 65536,
          bl + (size_t)(layer - 1) * 256, br + (size_t)(layer - 1) * 256, xl, xr, N);
      prev = xin;
    }

    float* xout = (layer & 1) ? xB : xA;
    k_fused<<<N, 64, 0, stream>>>(
        csrst, cnt, src_csr, ef_csr, xl, xr, prev,
        wet + (size_t)layer * 256 * 32, att + (size_t)layer * 256,
        conv_b + (size_t)layer * 256, ln_g + (size_t)layer * 256, ln_b + (size_t)layer * 256,
        xout);
    xin = xout;
  }

  k_out<<<512, 256, 0, stream>>>(xin, op_W1, op_b1, op_W2, op_b2, (float*)d_out, N);
}